// Round 2
// baseline (263.574 us; speedup 1.0000x reference)
//
#include <hip/hip_runtime.h>
#include <stdint.h>

// ---------------------------------------------------------------------------
// QConv1d fake-quant hardware simulation.
//   x: (4,16,2048) f32, weight: (64,16,7) f32, table: (61,1000) f32
//   out: (4,64,2042) f32
//
// Round-2 structure: interval-bound fast path.
//   For each output, compute an EXACT upper bound of the accumulator by
//   substituting per-row table max/min (monotone IEEE ops, identical fmaf
//   chain order) -> if the bound already quantizes to the clip floor (-8),
//   the true output is -8 and all 168 threefry evals are skipped.
//   ~99.95% of outputs take the fast path.
// ---------------------------------------------------------------------------

#define NELEM_TOT 43911168u  // 84 * 8168 * 64
#define RSTRIDE   522752u    // 8168 * 64
#define LOUT 2042
#define CO   64
#define CIN  16
#define LIN  2048
#define KW   7
#define DTOT 112             // CIN*KW
#define WSTR 116             // padded LDS stride (29 dwords, coprime with 32 banks)

__host__ __device__ __forceinline__ void tf2x32(uint32_t k0, uint32_t k1,
                                                uint32_t x0, uint32_t x1,
                                                uint32_t& o0, uint32_t& o1) {
  uint32_t ks2 = k0 ^ k1 ^ 0x1BD11BDAu;
  x0 += k0; x1 += k1;
#define TFR(r) { x0 += x1; x1 = (x1 << (r)) | (x1 >> (32 - (r))); x1 ^= x0; }
  TFR(13) TFR(15) TFR(26) TFR(6)
  x0 += k1;  x1 += ks2 + 1u;
  TFR(17) TFR(29) TFR(16) TFR(24)
  x0 += ks2; x1 += k0 + 2u;
  TFR(13) TFR(15) TFR(26) TFR(6)
  x0 += k0;  x1 += k1 + 3u;
  TFR(17) TFR(29) TFR(16) TFR(24)
  x0 += k1;  x1 += ks2 + 4u;
  TFR(13) TFR(15) TFR(26) TFR(6)
  x0 += ks2; x1 += k0 + 5u;
#undef TFR
  o0 = x0; o1 = x1;
}

__device__ __forceinline__ uint32_t randbits32(uint32_t ka, uint32_t kb, uint32_t i) {
  uint32_t o0, o1;
  tf2x32(ka, kb, 0u, i, o0, o1);
  return o0 ^ o1;
}

__device__ __forceinline__ int dot4(uint32_t xw, uint32_t ww) {
#if __has_builtin(__builtin_amdgcn_sdot4)
  return __builtin_amdgcn_sdot4((int)xw, (int)ww, 0, false);
#else
  int y2 = 0;
#pragma unroll
  for (int k = 0; k < 4; ++k) {
    int xbk = (int)((xw >> (8 * k)) & 0xffu);
    int wbk = (int)((int32_t)(ww << (24 - 8 * k)) >> 24);
    y2 += xbk * wbk;
  }
  return y2;
#endif
}

// ---- pre-kernel: per-row min/max of the table -> d_ws[0..60]=max, [61..121]=min
__global__ __launch_bounds__(256) void rowminmax_kernel(
    const float* __restrict__ table, float* __restrict__ ws) {
  __shared__ float smx[256], smn[256];
  const int row = blockIdx.x;
  const float* rp = table + row * 1000;
  float mx = -1e30f, mn = 1e30f;
  for (int i = threadIdx.x; i < 1000; i += 256) {
    float v = rp[i];
    mx = fmaxf(mx, v); mn = fminf(mn, v);
  }
  smx[threadIdx.x] = mx; smn[threadIdx.x] = mn;
  __syncthreads();
  for (int s = 128; s > 0; s >>= 1) {
    if (threadIdx.x < s) {
      smx[threadIdx.x] = fmaxf(smx[threadIdx.x], smx[threadIdx.x + s]);
      smn[threadIdx.x] = fminf(smn[threadIdx.x], smn[threadIdx.x + s]);
    }
    __syncthreads();
  }
  if (threadIdx.x == 0) { ws[row] = smx[0]; ws[61 + row] = smn[0]; }
}

__global__ __launch_bounds__(256) void qconv1d_kernel(
    const float* __restrict__ x, const float* __restrict__ w,
    const float* __restrict__ table, const float* __restrict__ rowmm,
    float* __restrict__ out,
    uint32_t k1a, uint32_t k1b, uint32_t k2a, uint32_t k2b) {
  __shared__ int8_t   w2[3 * 64 * WSTR];   // 2*{q_plus, q_minus_low, q_minus_high}
  __shared__ uint32_t xr4[4][28];          // x_int rows packed (6..14 per byte)
  __shared__ float    rmaxlut[841];        // (rowmax[yidx]+y15)-y15 per y2
  __shared__ float    rminlut[841];        // (rowmin[yidx]+y15)-y15 per y2
  __shared__ float    rmax[61], rmin[61];
  __shared__ float    biasv[64];
  __shared__ int      bias_i[64];

  const int tid = threadIdx.x;
  if (tid < 64) bias_i[tid] = 0;
  if (tid >= 64 && tid < 125) rmax[tid - 64] = rowmm[tid - 64];
  if (tid >= 128 && tid < 189) rmin[tid - 128] = rowmm[61 + tid - 128];
  __syncthreads();

  // ---- stage quantized weights: iw = rint(clip(w,-2,1.75)*4) in [-8,7] ----
  for (int task = tid; task < 64 * 28; task += 256) {
    int c = task / 28, q = task % 28, d0 = q * 4;
    uint32_t pp = 0, pl = 0, ph = 0;
    int siw = 0;
#pragma unroll
    for (int k = 0; k < 4; ++k) {
      float wv = w[c * DTOT + d0 + k];
      float wc = fminf(fmaxf(wv, -2.0f), 1.75f);
      int iw = (int)rintf(wc * 4.0f);
      siw += iw;
      int p  = iw > 0 ? iw : 0;                    // 2*q_plus
      int mh = (-iw - 2) > 0 ? (-iw - 2) : 0;      // 2*q_minus_high
      int ml = (iw < 0 ? -iw : 0) - 2 * mh;        // 2*q_minus_low
      pp |= (uint32_t)(p  & 0xff) << (8 * k);
      pl |= (uint32_t)(ml & 0xff) << (8 * k);
      ph |= (uint32_t)(mh & 0xff) << (8 * k);
    }
    int off = c * WSTR + d0;
    *(uint32_t*)&w2[0 * 64 * WSTR + off] = pp;
    *(uint32_t*)&w2[1 * 64 * WSTR + off] = pl;
    *(uint32_t*)&w2[2 * 64 * WSTR + off] = ph;
    atomicAdd(&bias_i[c], siw);
  }

  // ---- stage x_int rows: x_int = 2*rint(clip(x)*4) + 6 in {6..14} ----
  const int r0 = blockIdx.x * 4;
  {
    uint8_t* xr = (uint8_t*)xr4;
    for (int idx = tid; idx < 4 * DTOT; idx += 256) {
      int row = idx / DTOT, d = idx - row * DTOT;
      int cin = d / KW, kk = d - cin * KW;
      int r = r0 + row, b = r / LOUT, l = r - b * LOUT;
      float xv = x[(b * CIN + cin) * LIN + l + kk];
      float xc = fminf(fmaxf(xv, -2.0f), 1.75f);
      xr[row * DTOT + d] = (uint8_t)(2 * (int)rintf(xc * 4.0f) + 6);
    }
  }

  // ---- bound LUTs: per possible y2, the exact res upper/lower bound ----
  for (int i = tid; i < 841; i += 256) {
    int y2 = i - 448;
    int yi = y2 > 0 ? (y2 >> 1) : 0;
    yi = yi < 60 ? yi : 60;
    float y15 = ((float)y2 * 0.5f) / 15.0f;        // exact IEEE, matches ref
    rmaxlut[i] = (rmax[yi] + y15) - y15;
    rminlut[i] = (rmin[yi] + y15) - y15;
  }
  __syncthreads();
  if (tid < 64) biasv[tid] = 3.0f * (float)bias_i[tid];  // == 6*sum(q_int)
  __syncthreads();

  // ---- one thread per (r, c) output ----
  const int rl = tid >> 6, c = tid & 63;
  const int r = r0 + rl;
  const int b = r / LOUT, l = r - b * LOUT;
  float* outp = &out[(b * CO + c) * LOUT + l];
  const float bias = biasv[c];
  const float S15[3] = {15.0f, -15.0f, -30.0f};

  uint32_t xw[28];
#pragma unroll
  for (int g = 0; g < 28; ++g) xw[g] = xr4[rl][g];

  // ---- fast path: exact upper bound of the accumulator chain ----
  float accub = 0.0f;
#pragma unroll
  for (int t = 0; t < 3; ++t) {
    const float* lut = (t == 0) ? rmaxlut : rminlut;  // sign>0 -> max, else min
    const int8_t* wt = &w2[t * (64 * WSTR) + c * WSTR];
    const float s = S15[t];
#pragma unroll 4
    for (int g = 0; g < 28; ++g) {
      uint32_t ww = *(const uint32_t*)(wt + 4 * g);
      int y2 = dot4(xw[g], ww);
      accub = fmaf(s, lut[y2 + 448], accub);
    }
  }
  {
    float vub = (accub - bias) * 0.0625f;
    vub = fminf(fmaxf(vub, -8.0f), 7.75f);
    float qub = rintf(vub * 4.0f) * 0.25f;
    if (qub == -8.0f) {          // true acc <= accub (monotone chain) -> out=-8
      *outp = -8.0f;
      return;
    }
  }

  // ---- slow path: exact computation with threefry randoms (rare) ----
  const uint32_t base = (uint32_t)r * 64u + (uint32_t)c;
  float acc = 0.0f;
  for (int t = 0; t < 3; ++t) {
    const float s = S15[t];
    const int8_t* wt = &w2[t * (64 * WSTR) + c * WSTR];
    const uint32_t ib = base + (uint32_t)t * 28u * RSTRIDE;
    for (int g = 0; g < 28; ++g) {
      uint32_t i = ib + (uint32_t)g * RSTRIDE;     // flat C-order index (t,g,r,c)
      uint32_t hi = randbits32(k1a, k1b, i);
      uint32_t lo = randbits32(k2a, k2b, i);
      uint32_t rnd = ((hi % 1000u) * 296u + lo % 1000u) % 1000u;

      uint32_t ww = *(const uint32_t*)(wt + 4 * g);
      int y2 = dot4(xw[g], ww);
      int yidx = y2 > 0 ? (y2 >> 1) : 0;
      yidx = yidx < 60 ? yidx : 60;
      float y15 = ((float)y2 * 0.5f) / 15.0f;      // exact IEEE division
      float gv  = table[yidx * 1000 + (int)rnd];
      float res = (gv + y15) - y15;                // match ref rounding exactly
      acc = fmaf(s, res, acc);
    }
  }
  float v = (acc - bias) * 0.0625f;
  v = fminf(fmaxf(v, -8.0f), 7.75f);
  *outp = rintf(v * 4.0f) * 0.25f;
}

extern "C" void kernel_launch(void* const* d_in, const int* in_sizes, int n_in,
                              void* d_out, int out_size, void* d_ws, size_t ws_size,
                              hipStream_t stream) {
  const float* x     = (const float*)d_in[0];
  const float* w     = (const float*)d_in[1];
  const float* table = (const float*)d_in[2];
  float* out = (float*)d_out;
  float* ws  = (float*)d_ws;

  // Threefry subkeys from jax.random.key(1234), partitionable split
  uint32_t k1a, k1b, k2a, k2b;
  tf2x32(0u, 1234u, 0u, 0u, k1a, k1b);
  tf2x32(0u, 1234u, 0u, 1u, k2a, k2b);

  rowminmax_kernel<<<dim3(61), dim3(256), 0, stream>>>(table, ws);
  qconv1d_kernel<<<dim3(2042), dim3(256), 0, stream>>>(x, w, table, ws, out,
                                                       k1a, k1b, k2a, k2b);
}

// Round 3
// 237.871 us; speedup vs baseline: 1.1081x; 1.1081x over previous
//
#include <hip/hip_runtime.h>
#include <stdint.h>

// ---------------------------------------------------------------------------
// QConv1d fake-quant hardware simulation — round 3.
//   x: (4,16,2048) f32, weight: (64,16,7) f32, table: (61,1000) f32
//   out: (4,64,2042) f32
//
// Cost is irreducibly 2 threefry-2x32-20 evals per (t,g,r,c) element
// (44M elements). This version hand-tightens the inner loop:
//   - two threefry streams manually interleaved (independent dep chains)
//   - all key-injection constants prefolded on host -> SGPRs
//   - counter strength-reduced (i += RSTRIDE)
//   - exact y15 LUT in LDS (bit-exact vs ref's ((f32)y2*0.5f)/15.0f)
// ---------------------------------------------------------------------------

#define RSTRIDE   522752u    // 8168 * 64
#define LOUT 2042
#define CO   64
#define CIN  16
#define LIN  2048
#define KW   7
#define DTOT 112             // CIN*KW
#define WSTR 116             // padded LDS stride: 29 dwords, coprime with 32 banks

__host__ __device__ __forceinline__ void tf2x32(uint32_t k0, uint32_t k1,
                                                uint32_t x0, uint32_t x1,
                                                uint32_t& o0, uint32_t& o1) {
  uint32_t ks2 = k0 ^ k1 ^ 0x1BD11BDAu;
  x0 += k0; x1 += k1;
#define TFR(r) { x0 += x1; x1 = (x1 << (r)) | (x1 >> (32 - (r))); x1 ^= x0; }
  TFR(13) TFR(15) TFR(26) TFR(6)
  x0 += k1;  x1 += ks2 + 1u;
  TFR(17) TFR(29) TFR(16) TFR(24)
  x0 += ks2; x1 += k0 + 2u;
  TFR(13) TFR(15) TFR(26) TFR(6)
  x0 += k0;  x1 += k1 + 3u;
  TFR(17) TFR(29) TFR(16) TFR(24)
  x0 += k1;  x1 += ks2 + 4u;
  TFR(13) TFR(15) TFR(26) TFR(6)
  x0 += ks2; x1 += k0 + 5u;
#undef TFR
  o0 = x0; o1 = x1;
}

__device__ __forceinline__ int dot4(uint32_t xw, uint32_t ww) {
#if __has_builtin(__builtin_amdgcn_sdot4)
  return __builtin_amdgcn_sdot4((int)xw, (int)ww, 0, false);
#else
  int y2 = 0;
#pragma unroll
  for (int k = 0; k < 4; ++k) {
    int xbk = (int)((xw >> (8 * k)) & 0xffu);
    int wbk = (int)((int32_t)(ww << (24 - 8 * k)) >> 24);
    y2 += xbk * wbk;
  }
  return y2;
#endif
}

// 12 uniform constants per launch: for each stream {ka, kb, ks, c1..c5}
// packed as two arrays of 8 (ka, kb, ks, pad, c1, c2, c3, c4) + c5 separate
struct TfConsts {
  uint32_t a_ka, a_kb, a_ks, a_c1, a_c2, a_c3, a_c4, a_c5;
  uint32_t b_ka, b_kb, b_ks, b_c1, b_c2, b_c3, b_c4, b_c5;
};

__global__ __launch_bounds__(256) void qconv1d_kernel(
    const float* __restrict__ x, const float* __restrict__ w,
    const float* __restrict__ table, float* __restrict__ out, TfConsts K) {
  __shared__ int8_t   w2[3 * 64 * WSTR];   // 2*{q_plus, q_minus_low, q_minus_high}
  __shared__ uint32_t xr4[4][28];          // x_int rows packed (bytes 6..14)
  __shared__ float    y15lut[841];         // exact ((f32)y2*0.5f)/15.0f, y2 in [-448,392]
  __shared__ float    biasv[64];
  __shared__ int      bias_i[64];

  const int tid = threadIdx.x;
  if (tid < 64) bias_i[tid] = 0;
  __syncthreads();

  // ---- stage quantized weights: iw = rint(clip(w,-2,1.75)*4) in [-8,7] ----
  for (int task = tid; task < 64 * 28; task += 256) {
    int c = task / 28, q = task % 28, d0 = q * 4;
    uint32_t pp = 0, pl = 0, ph = 0;
    int siw = 0;
#pragma unroll
    for (int k = 0; k < 4; ++k) {
      float wv = w[c * DTOT + d0 + k];
      float wc = fminf(fmaxf(wv, -2.0f), 1.75f);
      int iw = (int)rintf(wc * 4.0f);
      siw += iw;
      int p  = iw > 0 ? iw : 0;                    // 2*q_plus
      int mh = (-iw - 2) > 0 ? (-iw - 2) : 0;      // 2*q_minus_high
      int ml = (iw < 0 ? -iw : 0) - 2 * mh;        // 2*q_minus_low
      pp |= (uint32_t)(p  & 0xff) << (8 * k);
      pl |= (uint32_t)(ml & 0xff) << (8 * k);
      ph |= (uint32_t)(mh & 0xff) << (8 * k);
    }
    int off = c * WSTR + d0;
    *(uint32_t*)&w2[0 * 64 * WSTR + off] = pp;
    *(uint32_t*)&w2[1 * 64 * WSTR + off] = pl;
    *(uint32_t*)&w2[2 * 64 * WSTR + off] = ph;
    atomicAdd(&bias_i[c], siw);
  }

  // ---- stage x_int rows: x_int = 2*rint(clip(x)*4) + 6 in {6..14} ----
  const int r0 = blockIdx.x * 4;
  {
    uint8_t* xr = (uint8_t*)xr4;
    for (int idx = tid; idx < 4 * DTOT; idx += 256) {
      int row = idx / DTOT, d = idx - row * DTOT;
      int cin = d / KW, kk = d - cin * KW;
      int r = r0 + row, b = r / LOUT, l = r - b * LOUT;
      float xv = x[(b * CIN + cin) * LIN + l + kk];
      float xc = fminf(fmaxf(xv, -2.0f), 1.75f);
      xr[row * DTOT + d] = (uint8_t)(2 * (int)rintf(xc * 4.0f) + 6);
    }
  }

  // ---- y15 LUT: exact IEEE y/15 for every possible y (y2 = 2*y) ----
  for (int i = tid; i < 841; i += 256) {
    y15lut[i] = ((float)(i - 448) * 0.5f) / 15.0f;
  }
  __syncthreads();
  if (tid < 64) biasv[tid] = 3.0f * (float)bias_i[tid];  // == 6*sum(q_int)
  __syncthreads();

  // ---- main: one thread per (r, c) output ----
  const int rl = tid >> 6, c = tid & 63;
  const int r = r0 + rl;
  const int b = r / LOUT, l = r - b * LOUT;
  const float bias = biasv[c];
  const float S15[3] = {15.0f, -15.0f, -30.0f};

  uint32_t i = (uint32_t)r * 64u + (uint32_t)c;  // flat C-order (t,g,r,c) counter
  float acc = 0.0f;

#define RND2(rr) { a0 += a1; a1 = (a1 << (rr)) | (a1 >> (32 - (rr))); a1 ^= a0; \
                   b0 += b1; b1 = (b1 << (rr)) | (b1 >> (32 - (rr))); b1 ^= b0; }

  for (int t = 0; t < 3; ++t) {
    const float s = S15[t];
    const int8_t* wt = &w2[t * (64 * WSTR) + c * WSTR];
#pragma unroll 2
    for (int g = 0; g < 28; ++g) {
      // two interleaved threefry-2x32-20 evals on counter (0, i)
      uint32_t a0 = K.a_ka, a1 = i + K.a_kb;
      uint32_t b0 = K.b_ka, b1 = i + K.b_kb;
      RND2(13) RND2(15) RND2(26) RND2(6)
      a0 += K.a_kb; a1 += K.a_c1;  b0 += K.b_kb; b1 += K.b_c1;
      RND2(17) RND2(29) RND2(16) RND2(24)
      a0 += K.a_ks; a1 += K.a_c2;  b0 += K.b_ks; b1 += K.b_c2;
      RND2(13) RND2(15) RND2(26) RND2(6)
      a0 += K.a_ka; a1 += K.a_c3;  b0 += K.b_ka; b1 += K.b_c3;
      RND2(17) RND2(29) RND2(16) RND2(24)
      a0 += K.a_kb; a1 += K.a_c4;  b0 += K.b_kb; b1 += K.b_c4;
      RND2(13) RND2(15) RND2(26) RND2(6)
      a0 += K.a_ks; a1 += K.a_c5;  b0 += K.b_ks; b1 += K.b_c5;
      uint32_t hi = a0 ^ a1, lo = b0 ^ b1;

      uint32_t rnd = ((hi % 1000u) * 296u + lo % 1000u) % 1000u;

      uint32_t ww = *(const uint32_t*)(wt + 4 * g);
      int y2 = dot4(xr4[rl][g], ww);
      int ym = y2 > 0 ? y2 : 0;
      int yidx = ym >> 1;
      yidx = yidx < 60 ? yidx : 60;
      float y15 = y15lut[y2 + 448];
      float gv  = table[yidx * 1000 + (int)rnd];
      float res = (gv + y15) - y15;                // match ref rounding exactly
      acc = fmaf(s, res, acc);

      i += RSTRIDE;
    }
  }
#undef RND2

  float v = (acc - bias) * 0.0625f;                // /16 exact
  v = fminf(fmaxf(v, -8.0f), 7.75f);
  out[(b * CO + c) * LOUT + l] = rintf(v * 4.0f) * 0.25f;  // fake_quant(.,2,6)
}

extern "C" void kernel_launch(void* const* d_in, const int* in_sizes, int n_in,
                              void* d_out, int out_size, void* d_ws, size_t ws_size,
                              hipStream_t stream) {
  const float* x     = (const float*)d_in[0];
  const float* w     = (const float*)d_in[1];
  const float* table = (const float*)d_in[2];
  float* out = (float*)d_out;

  // Threefry subkeys from jax.random.key(1234), partitionable split:
  //   k_i = tf(key, (0, i))
  uint32_t k1a, k1b, k2a, k2b;
  tf2x32(0u, 1234u, 0u, 0u, k1a, k1b);
  tf2x32(0u, 1234u, 0u, 1u, k2a, k2b);

  TfConsts K;
  K.a_ka = k1a; K.a_kb = k1b; K.a_ks = k1a ^ k1b ^ 0x1BD11BDAu;
  K.a_c1 = K.a_ks + 1u; K.a_c2 = k1a + 2u; K.a_c3 = k1b + 3u;
  K.a_c4 = K.a_ks + 4u; K.a_c5 = k1a + 5u;
  K.b_ka = k2a; K.b_kb = k2b; K.b_ks = k2a ^ k2b ^ 0x1BD11BDAu;
  K.b_c1 = K.b_ks + 1u; K.b_c2 = k2a + 2u; K.b_c3 = k2b + 3u;
  K.b_c4 = K.b_ks + 4u; K.b_c5 = k2a + 5u;

  qconv1d_kernel<<<dim3(2042), dim3(256), 0, stream>>>(x, w, table, out, K);
}

// Round 4
// 227.714 us; speedup vs baseline: 1.1575x; 1.0446x over previous
//
#include <hip/hip_runtime.h>
#include <stdint.h>

// ---------------------------------------------------------------------------
// QConv1d fake-quant hardware simulation — round 4.
//   x: (4,16,2048) f32, weight: (64,16,7) f32, table: (61,1000) f32
//   out: (4,64,2042) f32
//
// Cost is irreducibly 2 threefry-2x32-20 evals per (t,g,r,c) element (44M
// elements, ~132 VALU ops). Round-4 trims the non-threefry tail:
//   - final %1000 via exact float-reciprocal floor (full-rate cvt/mul/cvt
//     instead of quarter-rate v_mul_hi_u32 magic). Exact for n < 354K.
//   - __umul24 for q*1000 and table indexing (full-rate 24-bit mads)
//   - med3-matchable clamp for yidx
//   - unroll 4
// ---------------------------------------------------------------------------

#define RSTRIDE   522752u    // 8168 * 64
#define LOUT 2042
#define CO   64
#define CIN  16
#define LIN  2048
#define KW   7
#define DTOT 112             // CIN*KW
#define WSTR 116             // padded LDS stride: 29 dwords, coprime with 32 banks

__host__ __device__ __forceinline__ void tf2x32(uint32_t k0, uint32_t k1,
                                                uint32_t x0, uint32_t x1,
                                                uint32_t& o0, uint32_t& o1) {
  uint32_t ks2 = k0 ^ k1 ^ 0x1BD11BDAu;
  x0 += k0; x1 += k1;
#define TFR(r) { x0 += x1; x1 = (x1 << (r)) | (x1 >> (32 - (r))); x1 ^= x0; }
  TFR(13) TFR(15) TFR(26) TFR(6)
  x0 += k1;  x1 += ks2 + 1u;
  TFR(17) TFR(29) TFR(16) TFR(24)
  x0 += ks2; x1 += k0 + 2u;
  TFR(13) TFR(15) TFR(26) TFR(6)
  x0 += k0;  x1 += k1 + 3u;
  TFR(17) TFR(29) TFR(16) TFR(24)
  x0 += k1;  x1 += ks2 + 4u;
  TFR(13) TFR(15) TFR(26) TFR(6)
  x0 += ks2; x1 += k0 + 5u;
#undef TFR
  o0 = x0; o1 = x1;
}

__device__ __forceinline__ int dot4(uint32_t xw, uint32_t ww) {
#if __has_builtin(__builtin_amdgcn_sdot4)
  return __builtin_amdgcn_sdot4((int)xw, (int)ww, 0, false);
#else
  int y2 = 0;
#pragma unroll
  for (int k = 0; k < 4; ++k) {
    int xbk = (int)((xw >> (8 * k)) & 0xffu);
    int wbk = (int)((int32_t)(ww << (24 - 8 * k)) >> 24);
    y2 += xbk * wbk;
  }
  return y2;
#endif
}

// exact n % 1000 for n < 354000 via float reciprocal (all full-rate ops).
// proof: 0.001f = (1/1000)(1+4.75e-8); for n<354K the product before rounding
// is in [n/1000, n/1000+1.7e-5]; RN moves it <=ulp/2 (~1.5e-5); truncation
// of a value in (k, k+0.99904) yields exactly floor(n/1000).
__device__ __forceinline__ uint32_t mod1000_small(uint32_t n) {
  uint32_t q = (uint32_t)((float)n * 0.001f);
  return n - __umul24(q, 1000u);
}

struct TfConsts {
  uint32_t a_ka, a_kb, a_ks, a_c1, a_c2, a_c3, a_c4, a_c5;
  uint32_t b_ka, b_kb, b_ks, b_c1, b_c2, b_c3, b_c4, b_c5;
};

__global__ __launch_bounds__(256) void qconv1d_kernel(
    const float* __restrict__ x, const float* __restrict__ w,
    const float* __restrict__ table, float* __restrict__ out, TfConsts K) {
  __shared__ int8_t   w2[3 * 64 * WSTR];   // 2*{q_plus, q_minus_low, q_minus_high}
  __shared__ uint32_t xr4[4][28];          // x_int rows packed (bytes 6..14)
  __shared__ float    y15lut[841];         // exact ((f32)y2*0.5f)/15.0f
  __shared__ float    biasv[64];
  __shared__ int      bias_i[64];

  const int tid = threadIdx.x;
  if (tid < 64) bias_i[tid] = 0;
  __syncthreads();

  // ---- stage quantized weights: iw = rint(clip(w,-2,1.75)*4) in [-8,7] ----
  for (int task = tid; task < 64 * 28; task += 256) {
    int c = task / 28, q = task % 28, d0 = q * 4;
    uint32_t pp = 0, pl = 0, ph = 0;
    int siw = 0;
#pragma unroll
    for (int k = 0; k < 4; ++k) {
      float wv = w[c * DTOT + d0 + k];
      float wc = fminf(fmaxf(wv, -2.0f), 1.75f);
      int iw = (int)rintf(wc * 4.0f);
      siw += iw;
      int p  = iw > 0 ? iw : 0;                    // 2*q_plus
      int mh = (-iw - 2) > 0 ? (-iw - 2) : 0;      // 2*q_minus_high
      int ml = (iw < 0 ? -iw : 0) - 2 * mh;        // 2*q_minus_low
      pp |= (uint32_t)(p  & 0xff) << (8 * k);
      pl |= (uint32_t)(ml & 0xff) << (8 * k);
      ph |= (uint32_t)(mh & 0xff) << (8 * k);
    }
    int off = c * WSTR + d0;
    *(uint32_t*)&w2[0 * 64 * WSTR + off] = pp;
    *(uint32_t*)&w2[1 * 64 * WSTR + off] = pl;
    *(uint32_t*)&w2[2 * 64 * WSTR + off] = ph;
    atomicAdd(&bias_i[c], siw);
  }

  // ---- stage x_int rows: x_int = 2*rint(clip(x)*4) + 6 in {6..14} ----
  const int r0 = blockIdx.x * 4;
  {
    uint8_t* xr = (uint8_t*)xr4;
    for (int idx = tid; idx < 4 * DTOT; idx += 256) {
      int row = idx / DTOT, d = idx - row * DTOT;
      int cin = d / KW, kk = d - cin * KW;
      int r = r0 + row, b = r / LOUT, l = r - b * LOUT;
      float xv = x[(b * CIN + cin) * LIN + l + kk];
      float xc = fminf(fmaxf(xv, -2.0f), 1.75f);
      xr[row * DTOT + d] = (uint8_t)(2 * (int)rintf(xc * 4.0f) + 6);
    }
  }

  // ---- y15 LUT: exact IEEE y/15 for every possible y (y2 = 2*y) ----
  for (int i = tid; i < 841; i += 256) {
    y15lut[i] = ((float)(i - 448) * 0.5f) / 15.0f;
  }
  __syncthreads();
  if (tid < 64) biasv[tid] = 3.0f * (float)bias_i[tid];  // == 6*sum(q_int)
  __syncthreads();

  // ---- main: one thread per (r, c) output ----
  const int rl = tid >> 6, c = tid & 63;
  const int r = r0 + rl;
  const int b = r / LOUT, l = r - b * LOUT;
  const float bias = biasv[c];
  const float S15[3] = {15.0f, -15.0f, -30.0f};

  uint32_t i = (uint32_t)r * 64u + (uint32_t)c;  // flat C-order (t,g,r,c) counter
  float acc = 0.0f;

#define RND2(rr) { a0 += a1; a1 = (a1 << (rr)) | (a1 >> (32 - (rr))); a1 ^= a0; \
                   b0 += b1; b1 = (b1 << (rr)) | (b1 >> (32 - (rr))); b1 ^= b0; }

  for (int t = 0; t < 3; ++t) {
    const float s = S15[t];
    const int8_t* wt = &w2[t * (64 * WSTR) + c * WSTR];
#pragma unroll 4
    for (int g = 0; g < 28; ++g) {
      // two interleaved threefry-2x32-20 evals on counter (0, i)
      uint32_t a0 = K.a_ka, a1 = i + K.a_kb;
      uint32_t b0 = K.b_ka, b1 = i + K.b_kb;
      RND2(13) RND2(15) RND2(26) RND2(6)
      a0 += K.a_kb; a1 += K.a_c1;  b0 += K.b_kb; b1 += K.b_c1;
      RND2(17) RND2(29) RND2(16) RND2(24)
      a0 += K.a_ks; a1 += K.a_c2;  b0 += K.b_ks; b1 += K.b_c2;
      RND2(13) RND2(15) RND2(26) RND2(6)
      a0 += K.a_ka; a1 += K.a_c3;  b0 += K.b_ka; b1 += K.b_c3;
      RND2(17) RND2(29) RND2(16) RND2(24)
      a0 += K.a_kb; a1 += K.a_c4;  b0 += K.b_kb; b1 += K.b_c4;
      RND2(13) RND2(15) RND2(26) RND2(6)
      a0 += K.a_ks; a1 += K.a_c5;  b0 += K.b_ks; b1 += K.b_c5;
      uint32_t hi = a0 ^ a1, lo = b0 ^ b1;

      // rnd = ((hi%1000)*296 + lo%1000) % 1000
      uint32_t mh = hi % 1000u;
      uint32_t ml = lo % 1000u;
      uint32_t tt = __umul24(mh, 296u) + ml;       // < 296704
      uint32_t rnd = mod1000_small(tt);

      uint32_t ww = *(const uint32_t*)(wt + 4 * g);
      int y2 = dot4(xr4[rl][g], ww);
      int yc = y2 < 0 ? 0 : y2;                    // med3-matchable clamp
      yc = yc > 120 ? 120 : yc;
      int yidx = yc >> 1;                          // y2 even -> exact y
      float y15 = y15lut[y2 + 448];
      float gv  = table[__umul24((uint32_t)yidx, 1000u) + rnd];
      float res = (gv + y15) - y15;                // match ref rounding exactly
      acc = fmaf(s, res, acc);

      i += RSTRIDE;
    }
  }
#undef RND2

  float v = (acc - bias) * 0.0625f;                // /16 exact
  v = fminf(fmaxf(v, -8.0f), 7.75f);
  out[(b * CO + c) * LOUT + l] = rintf(v * 4.0f) * 0.25f;  // fake_quant(.,2,6)
}

extern "C" void kernel_launch(void* const* d_in, const int* in_sizes, int n_in,
                              void* d_out, int out_size, void* d_ws, size_t ws_size,
                              hipStream_t stream) {
  const float* x     = (const float*)d_in[0];
  const float* w     = (const float*)d_in[1];
  const float* table = (const float*)d_in[2];
  float* out = (float*)d_out;

  // Threefry subkeys from jax.random.key(1234), partitionable split:
  //   k_i = tf(key, (0, i))
  uint32_t k1a, k1b, k2a, k2b;
  tf2x32(0u, 1234u, 0u, 0u, k1a, k1b);
  tf2x32(0u, 1234u, 0u, 1u, k2a, k2b);

  TfConsts K;
  K.a_ka = k1a; K.a_kb = k1b; K.a_ks = k1a ^ k1b ^ 0x1BD11BDAu;
  K.a_c1 = K.a_ks + 1u; K.a_c2 = k1a + 2u; K.a_c3 = k1b + 3u;
  K.a_c4 = K.a_ks + 4u; K.a_c5 = k1a + 5u;
  K.b_ka = k2a; K.b_kb = k2b; K.b_ks = k2a ^ k2b ^ 0x1BD11BDAu;
  K.b_c1 = K.b_ks + 1u; K.b_c2 = k2a + 2u; K.b_c3 = k2b + 3u;
  K.b_c4 = K.b_ks + 4u; K.b_c5 = k2a + 5u;

  qconv1d_kernel<<<dim3(2042), dim3(256), 0, stream>>>(x, w, table, out, K);
}